// Round 1
// baseline (68.876 us; speedup 1.0000x reference)
//
#include <hip/hip_runtime.h>
#include <math.h>

#define SIDELEN 128
#define KCOEF 5

// exp2 / rcp via the HW transcendental unit (1-ulp approx; tolerance is 2% of max).
__device__ __forceinline__ float fexp2(float x) {
#if defined(__has_builtin) && __has_builtin(__builtin_amdgcn_exp2f)
    return __builtin_amdgcn_exp2f(x);
#else
    return exp2f(x);
#endif
}
__device__ __forceinline__ float frcp(float x) {
#if defined(__has_builtin) && __has_builtin(__builtin_amdgcn_rcpf)
    return __builtin_amdgcn_rcpf(x);
#else
    return 1.0f / x;
#endif
}

// One block per (batch, atom). 256 threads = 16x16 pixel patch centered on the
// atom; coverage radius >= 7 pixels. Truncation error <= 2048*12.6*exp(-1.32*49)
// ~ 1e-24 (threshold is 0.935 absolute). Each thread folds the K=5 Gaussian sum
// and issues at most one atomicAdd.
__global__ __launch_bounds__(256) void potential_scatter(
    const float* __restrict__ coords,   // (B, A, 3)
    const float* __restrict__ ffa,      // (A, K)
    const float* __restrict__ ffb,      // (A, K)
    float* __restrict__ out,            // (B, 128, 128) fp32, pre-zeroed
    int A)
{
    const int blk = blockIdx.x;
    const int a   = blk % A;
    const int b   = blk / A;

    const float* cp = coords + (size_t)(b * A + a) * 3;
    const float x = cp[0];
    const float y = cp[1];

    // Pixel-index space: pixel coordinate = index - 64  =>  atom position in
    // index space is coord + 64. Patch rows r0..r0+15 cover |r - u| <= 7.
    const float u = x + 64.0f;   // row (X) axis
    const float v = y + 64.0f;   // col (Y) axis
    const int r0 = (int)floorf(u) - 7;
    const int c0 = (int)floorf(v) - 7;

    const int tid = threadIdx.x;
    const int r = r0 + (tid >> 4);
    const int c = c0 + (tid & 15);

    const float dxf = (float)r - u;
    const float dyf = (float)c - v;
    const float d2  = dxf * dxf + dyf * dyf;

    // exp(-4pi^2/b * d2) = exp2(c2 * d2), c2 = -4pi^2*log2(e)/b
    // weight w = 4pi * a / b
    float val = 0.0f;
#pragma unroll
    for (int k = 0; k < KCOEF; ++k) {
        const float af = ffa[a * KCOEF + k];
        const float bf = ffb[a * KCOEF + k];
        const float rb = frcp(bf);
        const float c2 = -56.95531725f * rb;         // 4*pi^2 * log2(e) / b
        const float w  = 12.56637061f * af * rb;     // 4*pi * a / b
        val = fmaf(w, fexp2(c2 * d2), val);
    }

    if (val != 0.0f && r >= 0 && r < SIDELEN && c >= 0 && c < SIDELEN) {
        atomicAdd(out + ((size_t)b * (SIDELEN * SIDELEN) + r * SIDELEN + c), val);
    }
}

extern "C" void kernel_launch(void* const* d_in, const int* in_sizes, int n_in,
                              void* d_out, int out_size, void* d_ws, size_t ws_size,
                              hipStream_t stream) {
    const float* coords = (const float*)d_in[0];   // (B, A, 3)
    const float* ffa    = (const float*)d_in[1];   // (A, K)
    const float* ffb    = (const float*)d_in[2];   // (A, K)
    float* out = (float*)d_out;

    const int A = in_sizes[1] / KCOEF;
    const int B = in_sizes[0] / (3 * A);

    // Harness poisons d_out with 0xAA before every launch; we accumulate with
    // atomics, so zero it first (memset node is graph-capturable).
    hipMemsetAsync(d_out, 0, (size_t)out_size * sizeof(float), stream);

    potential_scatter<<<dim3(B * A), dim3(256), 0, stream>>>(coords, ffa, ffb, out, A);
}